// Round 9
// baseline (184.200 us; speedup 1.0000x reference)
//
#include <hip/hip_runtime.h>

#define F 128
#define NEG_SLOPE 0.2f
#define SHIFT 9
#define BPB 512          // bins per bucket = 1<<SHIFT
#define NBS 512          // max buckets / cnt_bb stride

typedef _Float16 f16_t;
typedef _Float16 f16x8 __attribute__((ext_vector_type(8)));
typedef _Float16 f16x2 __attribute__((ext_vector_type(2)));
typedef float f32x4 __attribute__((ext_vector_type(4)));

// ---------------- prep: composite matrices + projection vectors ----------------
__global__ __launch_bounds__(128) void prep_mats(
    const float* __restrict__ Wu, const float* __restrict__ Wr,
    const float* __restrict__ Ws, const float* __restrict__ Wn,
    const float* __restrict__ alu, const float* __restrict__ aru,
    const float* __restrict__ alr, const float* __restrict__ arr_,
    f16_t* __restrict__ Mtu, f16_t* __restrict__ Mtr, f16_t* __restrict__ Wts,
    float* __restrict__ wlu, float* __restrict__ wru,
    float* __restrict__ wlr, float* __restrict__ wrr)
{
    int b = blockIdx.x;
    int tid = threadIdx.x;
    if (b < 256) {
        int k = b & 127;
        const float* W = (b < 128) ? Wu : Wr;
        f16_t* M = (b < 128) ? Mtu : Mtr;
        float acc = 0.f;
        for (int t = 0; t < F; t++) acc += W[k * F + t] * Wn[t * F + tid];
        M[tid * F + k] = (f16_t)acc;
    } else if (b < 384) {
        int c = b - 256;
        Wts[c * F + tid] = (f16_t)Ws[tid * F + c];
    } else {
        int which = b - 384;
        const float* W = (which < 2) ? Wu : Wr;
        const float* a = (which == 0) ? alu : (which == 1) ? aru : (which == 2) ? alr : arr_;
        float acc = 0.f;
        for (int c = 0; c < F; c++) acc += W[tid * F + c] * a[c];
        float* o = (which == 0) ? wlu : (which == 1) ? wru : (which == 2) ? wlr : wrr;
        o[tid] = acc;
    }
}

// ---------------- cast + el/er (MFMA) merged with p1a bucket histogram ----------------

__global__ __launch_bounds__(256) void cast_p1a(
    const float* __restrict__ feat,
    const float* __restrict__ wlu, const float* __restrict__ wru,
    const float* __restrict__ wlr, const float* __restrict__ wrr,
    f16_t* __restrict__ featb,
    float* __restrict__ elu, float* __restrict__ eru,
    float* __restrict__ elr, float* __restrict__ err_,
    const int* __restrict__ dst_u, const int* __restrict__ dst_r,
    int* __restrict__ cnt_bb,
    int Eu, int Et, int N, int chunk, int n, int nbk)
{
    int b = blockIdx.x;
    int tid = threadIdx.x;
    if (b < 256) {
        __shared__ int hist[NBS];
        for (int i = tid; i < NBS; i += 256) hist[i] = 0;
        __syncthreads();
        int e0 = b * chunk;
        int e1 = e0 + chunk; if (e1 > Et) e1 = Et;
        int u1 = (e1 < Eu) ? e1 : Eu;
        for (int e = e0 + tid; e < u1; e += 256) {
            int bin = dst_u[e];
            atomicAdd(&hist[bin >> SHIFT], 1);
        }
        int r0 = (e0 > Eu) ? e0 : Eu;
        for (int e = r0 + tid; e < e1; e += 256) {
            int bin = N + dst_r[e - Eu];
            atomicAdd(&hist[bin >> SHIFT], 1);
        }
        __syncthreads();
        for (int i = tid; i < NBS; i += 256) cnt_bb[b * NBS + i] = hist[i];
        return;
    }
    // ---- cast + el/er via MFMA: wave handles 16 rows ----
    int fid = b - 256;
    int lane = tid & 63;
    int wave = tid >> 6;
    int lo = lane & 15, hi = lane >> 4;
    int base = fid * 64 + wave * 16;
    if (base >= n) return;
    int row = base + lo;
    if (row > n - 1) row = n - 1;
    const float* fp = feat + (size_t)row * F + hi * 8;
    f16_t* fb = featb + (size_t)row * F + hi * 8;
    const float* wsel = (lo == 0) ? wlu : (lo == 1) ? wru : (lo == 2) ? wlr : wrr;

    f32x4 acc = (f32x4){0.f, 0.f, 0.f, 0.f};
#pragma unroll
    for (int ks = 0; ks < 4; ks++) {
        float4 a0 = *(const float4*)(fp + ks * 32);
        float4 a1 = *(const float4*)(fp + ks * 32 + 4);
        f16x8 af;
        af[0] = (f16_t)a0.x; af[1] = (f16_t)a0.y; af[2] = (f16_t)a0.z; af[3] = (f16_t)a0.w;
        af[4] = (f16_t)a1.x; af[5] = (f16_t)a1.y; af[6] = (f16_t)a1.z; af[7] = (f16_t)a1.w;
        *(f16x8*)(fb + ks * 32) = af;
        f16x8 bf;
#pragma unroll
        for (int q = 0; q < 8; q++) bf[q] = (f16_t)0;
        if (lo < 4) {
            float4 b0 = *(const float4*)(wsel + ks * 32 + hi * 8);
            float4 b1 = *(const float4*)(wsel + ks * 32 + hi * 8 + 4);
            bf[0] = (f16_t)b0.x; bf[1] = (f16_t)b0.y; bf[2] = (f16_t)b0.z; bf[3] = (f16_t)b0.w;
            bf[4] = (f16_t)b1.x; bf[5] = (f16_t)b1.y; bf[6] = (f16_t)b1.z; bf[7] = (f16_t)b1.w;
        }
        acc = __builtin_amdgcn_mfma_f32_16x16x32_f16(af, bf, acc, 0, 0, 0);
    }
    if (lo < 4) {
        float* oarr = (lo == 0) ? elu : (lo == 1) ? eru : (lo == 2) ? elr : err_;
#pragma unroll
        for (int j = 0; j < 4; j++) {
            int r = base + hi * 4 + j;
            if (r < n) oarr[r] = acc[j];
        }
    }
}

// ---------------- scan per-bucket over blocks ----------------

__global__ __launch_bounds__(256) void scan_bb1(int* __restrict__ cnt_bb,
                                                int* __restrict__ btot, int nbk)
{
    int k = blockIdx.x;
    int tid = threadIdx.x;
    __shared__ int lds[256];
    int v = cnt_bb[tid * NBS + k];
    lds[tid] = v;
    __syncthreads();
    for (int off = 1; off < 256; off <<= 1) {
        int add = (tid >= off) ? lds[tid - off] : 0;
        __syncthreads();
        lds[tid] += add;
        __syncthreads();
    }
    cnt_bb[tid * NBS + k] = lds[tid] - v;   // exclusive, relative within bucket
    if (tid == 255) btot[k] = lds[255];
}

__global__ __launch_bounds__(512) void scan_bb2(const int* __restrict__ btot,
                                                int* __restrict__ bbase,
                                                int* __restrict__ rp,
                                                int nbk, int twoN, int Et)
{
    __shared__ int lds[512];
    int t = threadIdx.x;
    int v = (t < nbk) ? btot[t] : 0;
    lds[t] = v;
    __syncthreads();
    for (int off = 1; off < 512; off <<= 1) {
        int add = (t >= off) ? lds[t - off] : 0;
        __syncthreads();
        lds[t] += add;
        __syncthreads();
    }
    bbase[t] = lds[t] - v;   // exclusive; for t>=nbk this equals total = Et
    if (t == 0) rp[twoN] = Et;
}

// ---------------- p1b: scatter edges into bucket-sorted order (LDS cursors) ----------------
// payload packed u32: src (17b) | bin-low-9 (bits 17..25)

__global__ __launch_bounds__(256) void p1b_scatter(
    const int* __restrict__ src_u, const int* __restrict__ dst_u,
    const int* __restrict__ src_r, const int* __restrict__ dst_r,
    const int* __restrict__ cnt_bb, const int* __restrict__ bbase,
    unsigned* __restrict__ bucketed,
    int Eu, int Et, int N, int chunk, int nbk)
{
    int b = blockIdx.x;
    int tid = threadIdx.x;
    __shared__ int cur[NBS];
    for (int i = tid; i < nbk; i += 256) cur[i] = bbase[i] + cnt_bb[b * NBS + i];
    __syncthreads();
    int e0 = b * chunk;
    int e1 = e0 + chunk; if (e1 > Et) e1 = Et;
    int u1 = (e1 < Eu) ? e1 : Eu;
    for (int e = e0 + tid; e < u1; e += 256) {
        int bin = dst_u[e];
        int s = src_u[e];
        int pos = atomicAdd(&cur[bin >> SHIFT], 1);
        bucketed[pos] = (unsigned)s | ((unsigned)(bin & (BPB - 1)) << 17);
    }
    int r0 = (e0 > Eu) ? e0 : Eu;
    for (int e = r0 + tid; e < e1; e += 256) {
        int bin = N + dst_r[e - Eu];
        int s = src_r[e - Eu];
        int pos = atomicAdd(&cur[bin >> SHIFT], 1);
        bucketed[pos] = (unsigned)s | ((unsigned)(bin & (BPB - 1)) << 17);
    }
}

// ---------------- p2: per-bucket fine CSR permute (512 threads, 1 bin/thread) ----------

__global__ __launch_bounds__(512) void p2_build(
    const unsigned* __restrict__ bucketed, const int* __restrict__ bbase,
    int* __restrict__ rp, int* __restrict__ csr, int twoN)
{
    int k = blockIdx.x;
    int tid = threadIdx.x;       // 0..511, one bin each
    int beg = bbase[k], end = bbase[k + 1];
    __shared__ int hist[BPB];
    __shared__ int psum[512];
    hist[tid] = 0;
    __syncthreads();
    for (int i = beg + tid; i < end; i += 512) {
        unsigned w = bucketed[i];
        atomicAdd(&hist[(w >> 17) & (BPB - 1)], 1);
    }
    __syncthreads();
    int v = hist[tid];
    psum[tid] = v;
    __syncthreads();
    for (int off = 1; off < 512; off <<= 1) {
        int add = (tid >= off) ? psum[tid - off] : 0;
        __syncthreads();
        psum[tid] += add;
        __syncthreads();
    }
    int base = beg + psum[tid] - v;   // absolute exclusive base of bin tid
    int bin = (k << SHIFT) + tid;
    if (bin < twoN) rp[bin] = base;
    hist[tid] = base;                  // absolute cursor
    __syncthreads();
    for (int i = beg + tid; i < end; i += 512) {
        unsigned w = bucketed[i];
        int src = (int)(w & 0x1FFFF);
        int pos = atomicAdd(&hist[(w >> 17) & (BPB - 1)], 1);
        csr[pos] = src;
    }
}

// ---------------- fused aggregate + block-level MFMA epilogue ----------------
// Gather phase = v4 exactly: one dst per 16-lane group (4 dsts/wave), lane-local
// f16x2 accumulators, 2-edge unroll + 1-ahead row prefetch, inline exp.
// Epilogue: block's 4 waves own 16 consecutive dsts = one 16x128 A-tile.
// Normalized agg rows staged to 16 KB XOR-swizzled LDS; each wave computes 2 of
// the 8 column-tiles (acc[2] = 8 VGPR, live only after gather regs die).
// B-matrices (96 KB total) read from global -- L2-hot. Kills the aggu/aggr HBM
// round trip and the separate mfma_final3 kernel.

__global__ __launch_bounds__(256) void aggregate_final2(
    const f16_t* __restrict__ featb,
    const float* __restrict__ elu, const float* __restrict__ eru,
    const float* __restrict__ elr, const float* __restrict__ err_,
    const int* __restrict__ rp, const int* __restrict__ csr,
    const f16_t* __restrict__ Wts, const f16_t* __restrict__ Mtu,
    const f16_t* __restrict__ Mtr,
    const float* __restrict__ bn, const float* __restrict__ bias,
    float* __restrict__ out, int n)
{
    __shared__ f16_t Au[16 * F];   // 4 KB, XOR-swizzled 16B blocks
    __shared__ f16_t Ar[16 * F];   // 4 KB
    int tid = threadIdx.x;
    int lane = tid & 63;
    int wavIn = tid >> 6;          // 0..3
    int g = lane >> 4, lo = lane & 15;
    int blk0 = blockIdx.x * 16;
    int d16 = wavIn * 4 + g;       // 0..15: dst index within block tile
    int dst = blk0 + d16;
    bool alive = (dst < n);
    int dc = alive ? dst : (n - 1);

    int iu = rp[dc], endu = rp[dc + 1];
    int ir = rp[n + dc], endr = rp[n + dc + 1];
    if (!alive) { endu = iu; endr = ir; }
    float ervu = eru[dc];
    float ervr = err_[dc];

    union UV { f16x8 v; f16x2 p[4]; };
    f16x2 z = {(f16_t)0, (f16_t)0};
    f16x2 au0 = z, au1 = z, au2 = z, au3 = z;
    f16x2 ar0 = z, ar1 = z, ar2 = z, ar3 = z;
    float du = 0.f, dr = 0.f;

    // prologue: current pair per type
    bool vu0 = iu     < endu, vu1 = iu + 1 < endu;
    bool vr0 = ir     < endr, vr1 = ir + 1 < endr;
    int cu0 = csr[vu0 ? iu     : 0];
    int cu1 = csr[vu1 ? iu + 1 : 0];
    int cr0 = csr[vr0 ? ir     : 0];
    int cr1 = csr[vr1 ? ir + 1 : 0];
    UV hu0, hu1, hr0, hr1;
    hu0.v = *(const f16x8*)&featb[(size_t)cu0 * F + lo * 8];
    hu1.v = *(const f16x8*)&featb[(size_t)cu1 * F + lo * 8];
    hr0.v = *(const f16x8*)&featb[(size_t)cr0 * F + lo * 8];
    hr1.v = *(const f16x8*)&featb[(size_t)cr1 * F + lo * 8];

    while (iu < endu || ir < endr) {
        int ju = iu + 2, jr = ir + 2;
        // prefetch next pair's indices and rows
        bool nvu0 = ju     < endu, nvu1 = ju + 1 < endu;
        bool nvr0 = jr     < endr, nvr1 = jr + 1 < endr;
        int ncu0 = csr[nvu0 ? ju     : 0];
        int ncu1 = csr[nvu1 ? ju + 1 : 0];
        int ncr0 = csr[nvr0 ? jr     : 0];
        int ncr1 = csr[nvr1 ? jr + 1 : 0];
        UV pu0, pu1, pr0, pr1;
        pu0.v = *(const f16x8*)&featb[(size_t)ncu0 * F + lo * 8];
        pu1.v = *(const f16x8*)&featb[(size_t)ncu1 * F + lo * 8];
        pr0.v = *(const f16x8*)&featb[(size_t)ncr0 * F + lo * 8];
        pr1.v = *(const f16x8*)&featb[(size_t)ncr1 * F + lo * 8];

        // consume current pair (inline weight; invalid -> 0)
        {
            float e = elu[cu0] + ervu; e = fmaxf(e, NEG_SLOPE * e);
            float ex = vu0 ? __expf(e) : 0.f;
            f16_t w = (f16_t)ex; f16x2 wv = {w, w};
            au0 += wv * hu0.p[0]; au1 += wv * hu0.p[1];
            au2 += wv * hu0.p[2]; au3 += wv * hu0.p[3];
            du += ex;
        }
        {
            float e = elu[cu1] + ervu; e = fmaxf(e, NEG_SLOPE * e);
            float ex = vu1 ? __expf(e) : 0.f;
            f16_t w = (f16_t)ex; f16x2 wv = {w, w};
            au0 += wv * hu1.p[0]; au1 += wv * hu1.p[1];
            au2 += wv * hu1.p[2]; au3 += wv * hu1.p[3];
            du += ex;
        }
        {
            float e = elr[cr0] + ervr; e = fmaxf(e, NEG_SLOPE * e);
            float ex = vr0 ? __expf(e) : 0.f;
            f16_t w = (f16_t)ex; f16x2 wv = {w, w};
            ar0 += wv * hr0.p[0]; ar1 += wv * hr0.p[1];
            ar2 += wv * hr0.p[2]; ar3 += wv * hr0.p[3];
            dr += ex;
        }
        {
            float e = elr[cr1] + ervr; e = fmaxf(e, NEG_SLOPE * e);
            float ex = vr1 ? __expf(e) : 0.f;
            f16_t w = (f16_t)ex; f16x2 wv = {w, w};
            ar0 += wv * hr1.p[0]; ar1 += wv * hr1.p[1];
            ar2 += wv * hr1.p[2]; ar3 += wv * hr1.p[3];
            dr += ex;
        }

        // rotate pipeline
        hu0 = pu0; hu1 = pu1; hr0 = pr0; hr1 = pr1;
        cu0 = ncu0; cu1 = ncu1; cr0 = ncr0; cr1 = ncr1;
        vu0 = nvu0; vu1 = nvu1; vr0 = nvr0; vr1 = nvr1;
        iu = ju; ir = jr;
    }

    // normalize and stage to swizzled LDS (zeros for dead dsts)
    {
        float invu = (du > 0.f) ? 0.5f / du : 0.f;
        float invr = (dr > 0.f) ? 0.5f / dr : 0.f;
        f16_t ihu = (f16_t)invu, ihr = (f16_t)invr;
        f16x2 ivu = {ihu, ihu}, ivr = {ihr, ihr};
        UV ou, orr;
        ou.p[0] = au0 * ivu; ou.p[1] = au1 * ivu; ou.p[2] = au2 * ivu; ou.p[3] = au3 * ivu;
        orr.p[0] = ar0 * ivr; orr.p[1] = ar1 * ivr; orr.p[2] = ar2 * ivr; orr.p[3] = ar3 * ivr;
        int sb = ((lo ^ d16) & 15) * 8;   // swizzle: slot = datablock ^ row
        *(f16x8*)&Au[d16 * F + sb] = ou.v;
        *(f16x8*)&Ar[d16 * F + sb] = orr.v;
    }
    __syncthreads();

    // ---- epilogue: out[16 rows] = featb@Wts + Au@Mtu + Ar@Mtr + bn + bias ----
    // wave wavIn computes column tiles t0 = wavIn*2, t0+1.
    int lo2 = lo, hi2 = g;
    int t0 = wavIn * 2;
    float cb0 = bn[t0 * 16 + lo2]      + bias[t0 * 16 + lo2];
    float cb1 = bn[(t0 + 1) * 16 + lo2] + bias[(t0 + 1) * 16 + lo2];
    int arow = blk0 + lo2;
    if (arow > n - 1) arow = n - 1;
    const f16_t* pf = featb + (size_t)arow * F + hi2 * 8;
    int c0 = t0 * 16 + lo2;
    int c1 = c0 + 16;

    f32x4 acc0 = (f32x4){0.f, 0.f, 0.f, 0.f};
    f32x4 acc1 = (f32x4){0.f, 0.f, 0.f, 0.f};
#pragma unroll
    for (int ks = 0; ks < 4; ks++) {
        f16x8 a1 = *(const f16x8*)(pf + ks * 32);
        int kc = ks * 4 + hi2;
        int kcs = (kc ^ lo2) & 15;
        f16x8 a2 = *(const f16x8*)&Au[lo2 * F + kcs * 8];
        f16x8 a3 = *(const f16x8*)&Ar[lo2 * F + kcs * 8];
        int ko = ks * 32 + hi2 * 8;
        f16x8 bs0 = *(const f16x8*)&Wts[c0 * F + ko];
        f16x8 bu0 = *(const f16x8*)&Mtu[c0 * F + ko];
        f16x8 br0 = *(const f16x8*)&Mtr[c0 * F + ko];
        acc0 = __builtin_amdgcn_mfma_f32_16x16x32_f16(a1, bs0, acc0, 0, 0, 0);
        acc0 = __builtin_amdgcn_mfma_f32_16x16x32_f16(a2, bu0, acc0, 0, 0, 0);
        acc0 = __builtin_amdgcn_mfma_f32_16x16x32_f16(a3, br0, acc0, 0, 0, 0);
        f16x8 bs1 = *(const f16x8*)&Wts[c1 * F + ko];
        f16x8 bu1 = *(const f16x8*)&Mtu[c1 * F + ko];
        f16x8 br1 = *(const f16x8*)&Mtr[c1 * F + ko];
        acc1 = __builtin_amdgcn_mfma_f32_16x16x32_f16(a1, bs1, acc1, 0, 0, 0);
        acc1 = __builtin_amdgcn_mfma_f32_16x16x32_f16(a2, bu1, acc1, 0, 0, 0);
        acc1 = __builtin_amdgcn_mfma_f32_16x16x32_f16(a3, br1, acc1, 0, 0, 0);
    }

#pragma unroll
    for (int j = 0; j < 4; j++) {
        int r = blk0 + hi2 * 4 + j;
        if (r < n) {
            float* op = out + (size_t)r * F;
            op[t0 * 16 + lo2]       = acc0[j] + cb0;
            op[(t0 + 1) * 16 + lo2] = acc1[j] + cb1;
        }
    }
}

// ---------------- launch ----------------

extern "C" void kernel_launch(void* const* d_in, const int* in_sizes, int n_in,
                              void* d_out, int out_size, void* d_ws, size_t ws_size,
                              hipStream_t stream) {
    const float* feat   = (const float*)d_in[0];
    const int*   src_u  = (const int*)d_in[1];
    const int*   dst_u  = (const int*)d_in[2];
    const int*   src_r  = (const int*)d_in[3];
    const int*   dst_r  = (const int*)d_in[4];
    const float* W_self = (const float*)d_in[5];
    const float* W_u    = (const float*)d_in[6];
    const float* a_l_u  = (const float*)d_in[7];
    const float* a_r_u  = (const float*)d_in[8];
    const float* W_r    = (const float*)d_in[9];
    const float* a_l_r  = (const float*)d_in[10];
    const float* a_r_r  = (const float*)d_in[11];
    const float* W_ngh  = (const float*)d_in[12];
    const float* b_ngh  = (const float*)d_in[13];
    const float* bias   = (const float*)d_in[14];
    float* out = (float*)d_out;

    const int N  = in_sizes[0] / F;
    const int Eu = in_sizes[1];
    const int Er = in_sizes[3];
    const int Et = Eu + Er;
    const int twoN = 2 * N;
    const int nbk = (twoN + BPB - 1) >> SHIFT;   // buckets (<= NBS)

    char* ws = (char*)d_ws;
    size_t off = 0;
    auto alloc = [&](size_t bytes) -> void* {
        void* p = ws + off;
        off = (off + bytes + 255) & ~(size_t)255;
        return p;
    };
    f16_t* featb = (f16_t*)alloc((size_t)N * F * 2);
    f16_t* Mt_u  = (f16_t*)alloc((size_t)F * F * 2);
    f16_t* Mt_r  = (f16_t*)alloc((size_t)F * F * 2);
    f16_t* Wt_s  = (f16_t*)alloc((size_t)F * F * 2);
    float* wlu = (float*)alloc((size_t)F * 4);
    float* wru = (float*)alloc((size_t)F * 4);
    float* wlr = (float*)alloc((size_t)F * 4);
    float* wrr = (float*)alloc((size_t)F * 4);
    float* elu = (float*)alloc((size_t)N * 4);
    float* eru = (float*)alloc((size_t)N * 4);
    float* elr = (float*)alloc((size_t)N * 4);
    float* err_ = (float*)alloc((size_t)N * 4);
    int* cnt_bb = (int*)alloc((size_t)256 * NBS * 4);
    int* btot   = (int*)alloc((size_t)NBS * 4);
    int* bbase  = (int*)alloc((size_t)(NBS + 1) * 4);
    int* rp2    = (int*)alloc(((size_t)twoN + 1) * 4);
    unsigned* bucketed = (unsigned*)alloc((size_t)Et * 4);
    int* csr2   = (int*)alloc((size_t)Et * 4);

    prep_mats<<<388, 128, 0, stream>>>(W_u, W_r, W_self, W_ngh,
                                       a_l_u, a_r_u, a_l_r, a_r_r,
                                       Mt_u, Mt_r, Wt_s, wlu, wru, wlr, wrr);

    const int chunk = (Et + 255) / 256;
    int castBlocks = (N + 63) / 64;
    cast_p1a<<<256 + castBlocks, 256, 0, stream>>>(
        feat, wlu, wru, wlr, wrr, featb, elu, eru, elr, err_,
        dst_u, dst_r, cnt_bb, Eu, Et, N, chunk, N, nbk);

    scan_bb1<<<nbk, 256, 0, stream>>>(cnt_bb, btot, nbk);
    scan_bb2<<<1, 512, 0, stream>>>(btot, bbase, rp2, nbk, twoN, Et);
    p1b_scatter<<<256, 256, 0, stream>>>(src_u, dst_u, src_r, dst_r,
                                         cnt_bb, bbase, bucketed,
                                         Eu, Et, N, chunk, nbk);
    p2_build<<<nbk, 512, 0, stream>>>(bucketed, bbase, rp2, csr2, twoN);

    int nblk = (N + 15) / 16;
    aggregate_final2<<<nblk, 256, 0, stream>>>(featb, elu, eru, elr, err_,
                                               rp2, csr2, Wt_s, Mt_u, Mt_r,
                                               b_ngh, bias, out, N);
}

// Round 10
// 150.103 us; speedup vs baseline: 1.2272x; 1.2272x over previous
//
#include <hip/hip_runtime.h>

#define F 128
#define NEG_SLOPE 0.2f
#define SHIFT 9
#define BPB 512          // bins per bucket = 1<<SHIFT
#define NBS 512          // max buckets / cnt_bb stride
#define NCHUNK 512       // edge chunks (count/scatter parallelism)

typedef _Float16 f16_t;
typedef _Float16 f16x8 __attribute__((ext_vector_type(8)));
typedef _Float16 f16x2 __attribute__((ext_vector_type(2)));
typedef float f32x4 __attribute__((ext_vector_type(4)));

// ---------------- prep: composite matrices + projection vectors ----------------
__global__ __launch_bounds__(128) void prep_mats(
    const float* __restrict__ Wu, const float* __restrict__ Wr,
    const float* __restrict__ Ws, const float* __restrict__ Wn,
    const float* __restrict__ alu, const float* __restrict__ aru,
    const float* __restrict__ alr, const float* __restrict__ arr_,
    f16_t* __restrict__ Mtu, f16_t* __restrict__ Mtr, f16_t* __restrict__ Wts,
    float* __restrict__ wlu, float* __restrict__ wru,
    float* __restrict__ wlr, float* __restrict__ wrr)
{
    int b = blockIdx.x;
    int tid = threadIdx.x;
    if (b < 256) {
        int k = b & 127;
        const float* W = (b < 128) ? Wu : Wr;
        f16_t* M = (b < 128) ? Mtu : Mtr;
        float acc = 0.f;
        for (int t = 0; t < F; t++) acc += W[k * F + t] * Wn[t * F + tid];
        M[tid * F + k] = (f16_t)acc;
    } else if (b < 384) {
        int c = b - 256;
        Wts[c * F + tid] = (f16_t)Ws[tid * F + c];
    } else {
        int which = b - 384;
        const float* W = (which < 2) ? Wu : Wr;
        const float* a = (which == 0) ? alu : (which == 1) ? aru : (which == 2) ? alr : arr_;
        float acc = 0.f;
        for (int c = 0; c < F; c++) acc += W[tid * F + c] * a[c];
        float* o = (which == 0) ? wlu : (which == 1) ? wru : (which == 2) ? wlr : wrr;
        o[tid] = acc;
    }
}

// ---------------- cast + el/er (MFMA) merged with p1a bucket histogram ----------------
// blocks [0, NCHUNK): count; blocks [NCHUNK, ...): cast.

__global__ __launch_bounds__(256) void cast_p1a(
    const float* __restrict__ feat,
    const float* __restrict__ wlu, const float* __restrict__ wru,
    const float* __restrict__ wlr, const float* __restrict__ wrr,
    f16_t* __restrict__ featb,
    float* __restrict__ elu, float* __restrict__ eru,
    float* __restrict__ elr, float* __restrict__ err_,
    const int* __restrict__ dst_u, const int* __restrict__ dst_r,
    int* __restrict__ cnt_bb,
    int Eu, int Et, int N, int chunk, int n, int nbk)
{
    int b = blockIdx.x;
    int tid = threadIdx.x;
    if (b < NCHUNK) {
        __shared__ int hist[NBS];
        for (int i = tid; i < NBS; i += 256) hist[i] = 0;
        __syncthreads();
        int e0 = b * chunk;
        int e1 = e0 + chunk; if (e1 > Et) e1 = Et;
        int u1 = (e1 < Eu) ? e1 : Eu;
        for (int e = e0 + tid; e < u1; e += 256) {
            int bin = dst_u[e];
            atomicAdd(&hist[bin >> SHIFT], 1);
        }
        int r0 = (e0 > Eu) ? e0 : Eu;
        for (int e = r0 + tid; e < e1; e += 256) {
            int bin = N + dst_r[e - Eu];
            atomicAdd(&hist[bin >> SHIFT], 1);
        }
        __syncthreads();
        for (int i = tid; i < NBS; i += 256) cnt_bb[b * NBS + i] = hist[i];
        return;
    }
    // ---- cast + el/er via MFMA: wave handles 16 rows ----
    int fid = b - NCHUNK;
    int lane = tid & 63;
    int wave = tid >> 6;
    int lo = lane & 15, hi = lane >> 4;
    int base = fid * 64 + wave * 16;
    if (base >= n) return;
    int row = base + lo;
    if (row > n - 1) row = n - 1;
    const float* fp = feat + (size_t)row * F + hi * 8;
    f16_t* fb = featb + (size_t)row * F + hi * 8;
    const float* wsel = (lo == 0) ? wlu : (lo == 1) ? wru : (lo == 2) ? wlr : wrr;

    f32x4 acc = (f32x4){0.f, 0.f, 0.f, 0.f};
#pragma unroll
    for (int ks = 0; ks < 4; ks++) {
        float4 a0 = *(const float4*)(fp + ks * 32);
        float4 a1 = *(const float4*)(fp + ks * 32 + 4);
        f16x8 af;
        af[0] = (f16_t)a0.x; af[1] = (f16_t)a0.y; af[2] = (f16_t)a0.z; af[3] = (f16_t)a0.w;
        af[4] = (f16_t)a1.x; af[5] = (f16_t)a1.y; af[6] = (f16_t)a1.z; af[7] = (f16_t)a1.w;
        *(f16x8*)(fb + ks * 32) = af;
        f16x8 bf;
#pragma unroll
        for (int q = 0; q < 8; q++) bf[q] = (f16_t)0;
        if (lo < 4) {
            float4 b0 = *(const float4*)(wsel + ks * 32 + hi * 8);
            float4 b1 = *(const float4*)(wsel + ks * 32 + hi * 8 + 4);
            bf[0] = (f16_t)b0.x; bf[1] = (f16_t)b0.y; bf[2] = (f16_t)b0.z; bf[3] = (f16_t)b0.w;
            bf[4] = (f16_t)b1.x; bf[5] = (f16_t)b1.y; bf[6] = (f16_t)b1.z; bf[7] = (f16_t)b1.w;
        }
        acc = __builtin_amdgcn_mfma_f32_16x16x32_f16(af, bf, acc, 0, 0, 0);
    }
    if (lo < 4) {
        float* oarr = (lo == 0) ? elu : (lo == 1) ? eru : (lo == 2) ? elr : err_;
#pragma unroll
        for (int j = 0; j < 4; j++) {
            int r = base + hi * 4 + j;
            if (r < n) oarr[r] = acc[j];
        }
    }
}

// ---------------- scan per-bucket over chunks (512 threads = NCHUNK) ----------------

__global__ __launch_bounds__(512) void scan_bb1(int* __restrict__ cnt_bb,
                                                int* __restrict__ btot, int nbk)
{
    int k = blockIdx.x;
    int tid = threadIdx.x;
    __shared__ int lds[NCHUNK];
    int v = cnt_bb[tid * NBS + k];
    lds[tid] = v;
    __syncthreads();
    for (int off = 1; off < NCHUNK; off <<= 1) {
        int add = (tid >= off) ? lds[tid - off] : 0;
        __syncthreads();
        lds[tid] += add;
        __syncthreads();
    }
    cnt_bb[tid * NBS + k] = lds[tid] - v;   // exclusive, relative within bucket
    if (tid == NCHUNK - 1) btot[k] = lds[NCHUNK - 1];
}

__global__ __launch_bounds__(512) void scan_bb2(const int* __restrict__ btot,
                                                int* __restrict__ bbase,
                                                int* __restrict__ rp,
                                                int nbk, int twoN, int Et)
{
    __shared__ int lds[512];
    int t = threadIdx.x;
    int v = (t < nbk) ? btot[t] : 0;
    lds[t] = v;
    __syncthreads();
    for (int off = 1; off < 512; off <<= 1) {
        int add = (t >= off) ? lds[t - off] : 0;
        __syncthreads();
        lds[t] += add;
        __syncthreads();
    }
    bbase[t] = lds[t] - v;   // exclusive; for t>=nbk this equals total = Et
    if (t == 0) rp[twoN] = Et;
}

// ---------------- p1b: scatter edges into bucket-sorted order (LDS cursors) ----------------
// payload packed u32: src (17b) | bin-low-9 (bits 17..25)

__global__ __launch_bounds__(256) void p1b_scatter(
    const int* __restrict__ src_u, const int* __restrict__ dst_u,
    const int* __restrict__ src_r, const int* __restrict__ dst_r,
    const int* __restrict__ cnt_bb, const int* __restrict__ bbase,
    unsigned* __restrict__ bucketed,
    int Eu, int Et, int N, int chunk, int nbk)
{
    int b = blockIdx.x;
    int tid = threadIdx.x;
    __shared__ int cur[NBS];
    for (int i = tid; i < nbk; i += 256) cur[i] = bbase[i] + cnt_bb[b * NBS + i];
    __syncthreads();
    int e0 = b * chunk;
    int e1 = e0 + chunk; if (e1 > Et) e1 = Et;
    int u1 = (e1 < Eu) ? e1 : Eu;
    for (int e = e0 + tid; e < u1; e += 256) {
        int bin = dst_u[e];
        int s = src_u[e];
        int pos = atomicAdd(&cur[bin >> SHIFT], 1);
        bucketed[pos] = (unsigned)s | ((unsigned)(bin & (BPB - 1)) << 17);
    }
    int r0 = (e0 > Eu) ? e0 : Eu;
    for (int e = r0 + tid; e < e1; e += 256) {
        int bin = N + dst_r[e - Eu];
        int s = src_r[e - Eu];
        int pos = atomicAdd(&cur[bin >> SHIFT], 1);
        bucketed[pos] = (unsigned)s | ((unsigned)(bin & (BPB - 1)) << 17);
    }
}

// ---------------- p2: per-bucket fine CSR permute (512 threads, 1 bin/thread) ----------

__global__ __launch_bounds__(512) void p2_build(
    const unsigned* __restrict__ bucketed, const int* __restrict__ bbase,
    int* __restrict__ rp, int* __restrict__ csr, int twoN)
{
    int k = blockIdx.x;
    int tid = threadIdx.x;       // 0..511, one bin each
    int beg = bbase[k], end = bbase[k + 1];
    __shared__ int hist[BPB];
    __shared__ int psum[512];
    hist[tid] = 0;
    __syncthreads();
    for (int i = beg + tid; i < end; i += 512) {
        unsigned w = bucketed[i];
        atomicAdd(&hist[(w >> 17) & (BPB - 1)], 1);
    }
    __syncthreads();
    int v = hist[tid];
    psum[tid] = v;
    __syncthreads();
    for (int off = 1; off < 512; off <<= 1) {
        int add = (tid >= off) ? psum[tid - off] : 0;
        __syncthreads();
        psum[tid] += add;
        __syncthreads();
    }
    int base = beg + psum[tid] - v;   // absolute exclusive base of bin tid
    int bin = (k << SHIFT) + tid;
    if (bin < twoN) rp[bin] = base;
    hist[tid] = base;                  // absolute cursor
    __syncthreads();
    for (int i = beg + tid; i < end; i += 512) {
        unsigned w = bucketed[i];
        int src = (int)(w & 0x1FFFF);
        int pos = atomicAdd(&hist[(w >> 17) & (BPB - 1)], 1);
        csr[pos] = src;
    }
}

// ---------------- aggregate v4: one dst per 16-lane group, inline exp --------
// R5's winning structure (4 dsts/wave, lane-local accumulators, no cross-lane
// reduction) with inline weight computation (el arrays are L2-resident, the
// gathers ride free under the featb-row BW wall). 2-edge unroll + 1-ahead row
// prefetch: up to 8 row gathers in flight per wave.

__global__ __launch_bounds__(256) void aggregate_v4(
    const f16_t* __restrict__ featb,
    const float* __restrict__ elu, const float* __restrict__ eru,
    const float* __restrict__ elr, const float* __restrict__ err_,
    const int* __restrict__ rp, const int* __restrict__ csr,
    f16_t* __restrict__ aggu, f16_t* __restrict__ aggr, int n)
{
    int wave = (int)(((size_t)blockIdx.x * 256 + threadIdx.x) >> 6);
    int lane = threadIdx.x & 63;
    int g = lane >> 4, lo = lane & 15;
    int dst = wave * 4 + g;
    bool alive = (dst < n);
    int dc = alive ? dst : (n - 1);

    int iu = rp[dc], endu = rp[dc + 1];
    int ir = rp[n + dc], endr = rp[n + dc + 1];
    if (!alive) { endu = iu; endr = ir; }
    float ervu = eru[dc];
    float ervr = err_[dc];

    union UV { f16x8 v; f16x2 p[4]; };
    f16x2 z = {(f16_t)0, (f16_t)0};
    f16x2 au0 = z, au1 = z, au2 = z, au3 = z;
    f16x2 ar0 = z, ar1 = z, ar2 = z, ar3 = z;
    float du = 0.f, dr = 0.f;

    // prologue: current pair per type
    bool vu0 = iu     < endu, vu1 = iu + 1 < endu;
    bool vr0 = ir     < endr, vr1 = ir + 1 < endr;
    int cu0 = csr[vu0 ? iu     : 0];
    int cu1 = csr[vu1 ? iu + 1 : 0];
    int cr0 = csr[vr0 ? ir     : 0];
    int cr1 = csr[vr1 ? ir + 1 : 0];
    UV hu0, hu1, hr0, hr1;
    hu0.v = *(const f16x8*)&featb[(size_t)cu0 * F + lo * 8];
    hu1.v = *(const f16x8*)&featb[(size_t)cu1 * F + lo * 8];
    hr0.v = *(const f16x8*)&featb[(size_t)cr0 * F + lo * 8];
    hr1.v = *(const f16x8*)&featb[(size_t)cr1 * F + lo * 8];

    while (iu < endu || ir < endr) {
        int ju = iu + 2, jr = ir + 2;
        // prefetch next pair's indices and rows
        bool nvu0 = ju     < endu, nvu1 = ju + 1 < endu;
        bool nvr0 = jr     < endr, nvr1 = jr + 1 < endr;
        int ncu0 = csr[nvu0 ? ju     : 0];
        int ncu1 = csr[nvu1 ? ju + 1 : 0];
        int ncr0 = csr[nvr0 ? jr     : 0];
        int ncr1 = csr[nvr1 ? jr + 1 : 0];
        UV pu0, pu1, pr0, pr1;
        pu0.v = *(const f16x8*)&featb[(size_t)ncu0 * F + lo * 8];
        pu1.v = *(const f16x8*)&featb[(size_t)ncu1 * F + lo * 8];
        pr0.v = *(const f16x8*)&featb[(size_t)ncr0 * F + lo * 8];
        pr1.v = *(const f16x8*)&featb[(size_t)ncr1 * F + lo * 8];

        // consume current pair (inline weight; invalid -> 0)
        {
            float e = elu[cu0] + ervu; e = fmaxf(e, NEG_SLOPE * e);
            float ex = vu0 ? __expf(e) : 0.f;
            f16_t w = (f16_t)ex; f16x2 wv = {w, w};
            au0 += wv * hu0.p[0]; au1 += wv * hu0.p[1];
            au2 += wv * hu0.p[2]; au3 += wv * hu0.p[3];
            du += ex;
        }
        {
            float e = elu[cu1] + ervu; e = fmaxf(e, NEG_SLOPE * e);
            float ex = vu1 ? __expf(e) : 0.f;
            f16_t w = (f16_t)ex; f16x2 wv = {w, w};
            au0 += wv * hu1.p[0]; au1 += wv * hu1.p[1];
            au2 += wv * hu1.p[2]; au3 += wv * hu1.p[3];
            du += ex;
        }
        {
            float e = elr[cr0] + ervr; e = fmaxf(e, NEG_SLOPE * e);
            float ex = vr0 ? __expf(e) : 0.f;
            f16_t w = (f16_t)ex; f16x2 wv = {w, w};
            ar0 += wv * hr0.p[0]; ar1 += wv * hr0.p[1];
            ar2 += wv * hr0.p[2]; ar3 += wv * hr0.p[3];
            dr += ex;
        }
        {
            float e = elr[cr1] + ervr; e = fmaxf(e, NEG_SLOPE * e);
            float ex = vr1 ? __expf(e) : 0.f;
            f16_t w = (f16_t)ex; f16x2 wv = {w, w};
            ar0 += wv * hr1.p[0]; ar1 += wv * hr1.p[1];
            ar2 += wv * hr1.p[2]; ar3 += wv * hr1.p[3];
            dr += ex;
        }

        // rotate pipeline
        hu0 = pu0; hu1 = pu1; hr0 = pr0; hr1 = pr1;
        cu0 = ncu0; cu1 = ncu1; cr0 = ncr0; cr1 = ncr1;
        vu0 = nvu0; vu1 = nvu1; vr0 = nvr0; vr1 = nvr1;
        iu = ju; ir = jr;
    }

    if (alive) {
        float invu = (du > 0.f) ? 0.5f / du : 0.f;
        float invr = (dr > 0.f) ? 0.5f / dr : 0.f;
        f16_t ihu = (f16_t)invu, ihr = (f16_t)invr;
        f16x2 ivu = {ihu, ihu}, ivr = {ihr, ihr};
        UV ou, orr;
        ou.p[0] = au0 * ivu; ou.p[1] = au1 * ivu; ou.p[2] = au2 * ivu; ou.p[3] = au3 * ivu;
        orr.p[0] = ar0 * ivr; orr.p[1] = ar1 * ivr; orr.p[2] = ar2 * ivr; orr.p[3] = ar3 * ivr;
        *(f16x8*)&aggu[(size_t)dst * F + lo * 8] = ou.v;
        *(f16x8*)&aggr[(size_t)dst * F + lo * 8] = orr.v;
    }
}

// ---------------- final: out = featb@Wts + aggu@Mtu + aggr@Mtr + bn + bias ----------------

__global__ __launch_bounds__(1024) void mfma_final3(
    const f16_t* __restrict__ featb,
    const f16_t* __restrict__ aggu, const f16_t* __restrict__ aggr,
    const f16_t* __restrict__ Wts, const f16_t* __restrict__ Mtu,
    const f16_t* __restrict__ Mtr,
    const float* __restrict__ bn, const float* __restrict__ bias,
    float* __restrict__ out, int n, int ntiles)
{
    __shared__ f16_t Ls[F * F];
    __shared__ f16_t Lu[F * F];
    __shared__ f16_t Lr[F * F];
    for (int i = threadIdx.x; i < 2048; i += 1024) {
        int c = i >> 4, kc = i & 15, kcs = kc ^ (c & 15);
        *(f16x8*)&Ls[c * F + kcs * 8] = *(const f16x8*)&Wts[c * F + kc * 8];
        *(f16x8*)&Lu[c * F + kcs * 8] = *(const f16x8*)&Mtu[c * F + kc * 8];
        *(f16x8*)&Lr[c * F + kcs * 8] = *(const f16x8*)&Mtr[c * F + kc * 8];
    }
    __syncthreads();

    int lane = threadIdx.x & 63;
    int wave = threadIdx.x >> 6;
    int lo = lane & 15, hi = lane >> 4;

    float cb[8];
#pragma unroll
    for (int t = 0; t < 8; t++) cb[t] = bn[t * 16 + lo] + bias[t * 16 + lo];

    for (int tile = blockIdx.x; tile < ntiles; tile += 256) {
        int row0 = tile * 256 + wave * 16;
        if (row0 >= n) continue;
        int arow = row0 + lo;
        if (arow > n - 1) arow = n - 1;
        const f16_t* pf = featb + (size_t)arow * F + hi * 8;
        const f16_t* pu = aggu + (size_t)arow * F + hi * 8;
        const f16_t* pr = aggr + (size_t)arow * F + hi * 8;

        f32x4 acc[8];
#pragma unroll
        for (int t = 0; t < 8; t++) acc[t] = (f32x4){0.f, 0.f, 0.f, 0.f};

#pragma unroll
        for (int ks = 0; ks < 4; ks++) {
            f16x8 a1 = *(const f16x8*)(pf + ks * 32);
            f16x8 a2 = *(const f16x8*)(pu + ks * 32);
            f16x8 a3 = *(const f16x8*)(pr + ks * 32);
#pragma unroll
            for (int t = 0; t < 8; t++) {
                int c = t * 16 + lo;
                int kcs = (ks * 4 + hi) ^ lo;
                f16x8 bs = *(const f16x8*)&Ls[c * F + kcs * 8];
                f16x8 bu = *(const f16x8*)&Lu[c * F + kcs * 8];
                f16x8 br = *(const f16x8*)&Lr[c * F + kcs * 8];
                acc[t] = __builtin_amdgcn_mfma_f32_16x16x32_f16(a1, bs, acc[t], 0, 0, 0);
                acc[t] = __builtin_amdgcn_mfma_f32_16x16x32_f16(a2, bu, acc[t], 0, 0, 0);
                acc[t] = __builtin_amdgcn_mfma_f32_16x16x32_f16(a3, br, acc[t], 0, 0, 0);
            }
        }

#pragma unroll
        for (int j = 0; j < 4; j++) {
            int r = row0 + hi * 4 + j;
            if (r < n) {
                float* op = out + (size_t)r * F + lo;
#pragma unroll
                for (int t = 0; t < 8; t++) op[t * 16] = acc[t][j] + cb[t];
            }
        }
    }
}

// ---------------- launch ----------------

extern "C" void kernel_launch(void* const* d_in, const int* in_sizes, int n_in,
                              void* d_out, int out_size, void* d_ws, size_t ws_size,
                              hipStream_t stream) {
    const float* feat   = (const float*)d_in[0];
    const int*   src_u  = (const int*)d_in[1];
    const int*   dst_u  = (const int*)d_in[2];
    const int*   src_r  = (const int*)d_in[3];
    const int*   dst_r  = (const int*)d_in[4];
    const float* W_self = (const float*)d_in[5];
    const float* W_u    = (const float*)d_in[6];
    const float* a_l_u  = (const float*)d_in[7];
    const float* a_r_u  = (const float*)d_in[8];
    const float* W_r    = (const float*)d_in[9];
    const float* a_l_r  = (const float*)d_in[10];
    const float* a_r_r  = (const float*)d_in[11];
    const float* W_ngh  = (const float*)d_in[12];
    const float* b_ngh  = (const float*)d_in[13];
    const float* bias   = (const float*)d_in[14];
    float* out = (float*)d_out;

    const int N  = in_sizes[0] / F;
    const int Eu = in_sizes[1];
    const int Er = in_sizes[3];
    const int Et = Eu + Er;
    const int twoN = 2 * N;
    const int nbk = (twoN + BPB - 1) >> SHIFT;   // buckets (<= NBS)

    char* ws = (char*)d_ws;
    size_t off = 0;
    auto alloc = [&](size_t bytes) -> void* {
        void* p = ws + off;
        off = (off + bytes + 255) & ~(size_t)255;
        return p;
    };
    f16_t* featb = (f16_t*)alloc((size_t)N * F * 2);
    f16_t* aggu  = (f16_t*)alloc((size_t)N * F * 2);
    f16_t* aggr  = (f16_t*)alloc((size_t)N * F * 2);
    f16_t* Mt_u  = (f16_t*)alloc((size_t)F * F * 2);
    f16_t* Mt_r  = (f16_t*)alloc((size_t)F * F * 2);
    f16_t* Wt_s  = (f16_t*)alloc((size_t)F * F * 2);
    float* wlu = (float*)alloc((size_t)F * 4);
    float* wru = (float*)alloc((size_t)F * 4);
    float* wlr = (float*)alloc((size_t)F * 4);
    float* wrr = (float*)alloc((size_t)F * 4);
    float* elu = (float*)alloc((size_t)N * 4);
    float* eru = (float*)alloc((size_t)N * 4);
    float* elr = (float*)alloc((size_t)N * 4);
    float* err_ = (float*)alloc((size_t)N * 4);
    int* cnt_bb = (int*)alloc((size_t)NCHUNK * NBS * 4);
    int* btot   = (int*)alloc((size_t)NBS * 4);
    int* bbase  = (int*)alloc((size_t)(NBS + 1) * 4);
    int* rp2    = (int*)alloc(((size_t)twoN + 1) * 4);
    unsigned* bucketed = (unsigned*)alloc((size_t)Et * 4);
    int* csr2   = (int*)alloc((size_t)Et * 4);

    prep_mats<<<388, 128, 0, stream>>>(W_u, W_r, W_self, W_ngh,
                                       a_l_u, a_r_u, a_l_r, a_r_r,
                                       Mt_u, Mt_r, Wt_s, wlu, wru, wlr, wrr);

    const int chunk = (Et + NCHUNK - 1) / NCHUNK;
    int castBlocks = (N + 63) / 64;
    cast_p1a<<<NCHUNK + castBlocks, 256, 0, stream>>>(
        feat, wlu, wru, wlr, wrr, featb, elu, eru, elr, err_,
        dst_u, dst_r, cnt_bb, Eu, Et, N, chunk, N, nbk);

    scan_bb1<<<nbk, 512, 0, stream>>>(cnt_bb, btot, nbk);
    scan_bb2<<<1, 512, 0, stream>>>(btot, bbase, rp2, nbk, twoN, Et);
    p1b_scatter<<<NCHUNK, 256, 0, stream>>>(src_u, dst_u, src_r, dst_r,
                                            cnt_bb, bbase, bucketed,
                                            Eu, Et, N, chunk, nbk);
    p2_build<<<nbk, 512, 0, stream>>>(bucketed, bbase, rp2, csr2, twoN);

    aggregate_v4<<<(N + 15) / 16, 256, 0, stream>>>(featb, elu, eru, elr, err_,
                                                    rp2, csr2, aggu, aggr, N);
    int ntiles = (N + 255) / 256;
    mfma_final3<<<256, 1024, 0, stream>>>(featb, aggu, aggr,
                                          Wt_s, Mt_u, Mt_r,
                                          b_ngh, bias, out, N, ntiles);
}